// Round 13
// baseline (6254.550 us; speedup 1.0000x reference)
//
#include <hip/hip_runtime.h>
#include <hip/hip_bf16.h>

#define IN_F 4096
#define OUT_F 4096
#define CPN 81
#define OINV 2225   // 81^{-1} mod 4096
#define OB16 2832   // 2225*16 mod 4096: o-step per group

#define BMF 8       // batch rows per block
#define NCH 8       // chunks per block
#define CHUNK 512   // band-starts (and x cols) per chunk
#define SC4 148     // float4 staged per row per chunk (592 cols)
#define NLD 1184    // BMF*SC4 loads per chunk
#define XSTR 616    // x LDS stride in shorts
#define RSTRF 8     // res stride in shorts (16 B per o-row)

typedef __attribute__((ext_vector_type(4))) float f32x4;
typedef __attribute__((ext_vector_type(8))) short bf16x8;

__device__ __forceinline__ unsigned short f2bf(float f) {
  __hip_bfloat16 h = __float2bfloat16(f);
  return *reinterpret_cast<unsigned short*>(&h);
}
__device__ __forceinline__ float bf2f(unsigned short u) {
  unsigned int v = ((unsigned int)u) << 16;
  return *reinterpret_cast<float*>(&v);
}

// ---- prep: pack weight*mask into MFMA B-fragment order ----
__global__ void prep_wfrag(const float* __restrict__ w,
                           const float* __restrict__ mask,
                           unsigned short* __restrict__ wfrag) {
  int idx = blockIdx.x * 256 + threadIdx.x;   // 49152 threads
  int lane = idx & 63;
  int t = (idx >> 6) % 3;
  int g = idx / 192;
  int n = lane & 15;
  int kg = lane >> 4;
  int s = g * 16 + n;
  int o = (OINV * s) & 4095;
  unsigned short v8[8];
#pragma unroll
  for (int i = 0; i < 8; ++i) {
    int c = 32 * t + 8 * kg + i;
    int j = c - n;
    float v = 0.f;
    if (j >= 0 && j < CPN) {
      int col = (16 * g + c) & 4095;
      v = w[(size_t)o * IN_F + col] * mask[(size_t)o * IN_F + col];
    }
    v8[i] = f2bf(v);
  }
  *reinterpret_cast<bf16x8*>(wfrag + (size_t)idx * 8) =
      *reinterpret_cast<const bf16x8*>(v8);
}

// ---- ablation probe: R8 kernel with phase flags ----
// MODE bits: 1=STAGE (x load+drain), 2=COMPUTE (wf+ds_read+MFMA+scatter),
//            4=EPILOGUE (res->out), 8=BARRIERS (__syncthreads vs none)
template <int MODE, int REP>
__global__ __launch_bounds__(512, 4) void sc_probe(
    const float* __restrict__ x, const float* __restrict__ bias,
    const unsigned short* __restrict__ wfrag, float* __restrict__ out) {
  constexpr bool STG = (MODE & 1) != 0;
  constexpr bool CMP = (MODE & 2) != 0;
  constexpr bool EPI = (MODE & 4) != 0;
  constexpr bool BAR = (MODE & 8) != 0;

  __shared__ unsigned short res[4096 * RSTRF];   // 65536 B
  __shared__ unsigned short xl[BMF * XSTR];      //  9856 B

  const int blk = blockIdx.x;        // 0..2047
  const int b0 = blk * BMF;
  const int tid = threadIdx.x;
  const int wave = tid >> 6;
  const int lane = tid & 63;
  const int ln = lane & 15;
  const int lk = lane >> 4;
  const int oln = (OINV * ln) & 4095;
  const int q0 = blk & 7;

  const int i1 = tid + 512, i2 = tid + 1024;
  const int row0 = tid / SC4, c40 = tid - row0 * SC4;
  const int row1 = i1 / SC4,  c41 = i1 - row1 * SC4;
  const int row2 = i2 / SC4,  c42 = i2 - row2 * SC4;
  const bool v2 = (i2 < NLD);
  const float* xp0 = x + (size_t)(b0 + row0) * IN_F;
  const float* xp1 = x + (size_t)(b0 + row1) * IN_F;
  const float* xp2 = x + (size_t)(b0 + row2) * IN_F;
  unsigned short* xw0 = xl + row0 * XSTR + 4 * c40;
  unsigned short* xw1 = xl + row1 * XSTR + 4 * c41;
  unsigned short* xw2 = xl + row2 * XSTR + 4 * c42;

  auto bar = [&]() {
    if constexpr (BAR) __syncthreads();
    else __builtin_amdgcn_sched_barrier(0);
  };
  auto loadx = [&](int q, float4& r0, float4& r1, float4& r2) {
    const int c0 = q * CHUNK;
    r0 = *reinterpret_cast<const float4*>(xp0 + ((c0 + 4 * c40) & 4095));
    r1 = *reinterpret_cast<const float4*>(xp1 + ((c0 + 4 * c41) & 4095));
    if (v2) r2 = *reinterpret_cast<const float4*>(xp2 + ((c0 + 4 * c42) & 4095));
  };
  auto drain = [&](const float4& r0, const float4& r1, const float4& r2) {
    ushort4 h;
    h.x = f2bf(r0.x); h.y = f2bf(r0.y); h.z = f2bf(r0.z); h.w = f2bf(r0.w);
    *reinterpret_cast<ushort4*>(xw0) = h;
    h.x = f2bf(r1.x); h.y = f2bf(r1.y); h.z = f2bf(r1.z); h.w = f2bf(r1.w);
    *reinterpret_cast<ushort4*>(xw1) = h;
    if (v2) {
      h.x = f2bf(r2.x); h.y = f2bf(r2.y); h.z = f2bf(r2.z); h.w = f2bf(r2.w);
      *reinterpret_cast<ushort4*>(xw2) = h;
    }
  };
  auto grp = [&](int g, const unsigned short* ap,
                 bf16x8 b0f, bf16x8 b1f, bf16x8 b2f) {
    bf16x8 a0 = *reinterpret_cast<const bf16x8*>(ap);
    bf16x8 a1 = *reinterpret_cast<const bf16x8*>(ap + 32);
    bf16x8 a2 = *reinterpret_cast<const bf16x8*>(ap + 64);
    f32x4 acc = f32x4{0.f, 0.f, 0.f, 0.f};
    acc = __builtin_amdgcn_mfma_f32_16x16x32_bf16(a0, b0f, acc, 0, 0, 0);
    acc = __builtin_amdgcn_mfma_f32_16x16x32_bf16(a1, b1f, acc, 0, 0, 0);
    acc = __builtin_amdgcn_mfma_f32_16x16x32_bf16(a2, b2f, acc, 0, 0, 0);
    if (lk < 2) {
      int o = (OB16 * g + oln) & 4095;
      ushort4 h;
      h.x = f2bf(acc[0]); h.y = f2bf(acc[1]);
      h.z = f2bf(acc[2]); h.w = f2bf(acc[3]);
      *reinterpret_cast<ushort4*>(res + o * RSTRF + 4 * lk) = h;
    }
  };
  auto compute = [&](int q) {
    const int gbase = q * 32 + wave * 4;
    const bf16x8* wf = reinterpret_cast<const bf16x8*>(wfrag)
                     + (size_t)gbase * 192 + lane;
    bf16x8 w0 = wf[0],   w1 = wf[64],  w2  = wf[128];
    bf16x8 w3 = wf[192], w4 = wf[256], w5  = wf[320];
    bf16x8 w6 = wf[384], w7 = wf[448], w8  = wf[512];
    bf16x8 w9 = wf[576], w10 = wf[640], w11 = wf[704];
    const unsigned short* ap = xl + (ln & 7) * XSTR + 8 * lk + 16 * (wave * 4);
    grp(gbase + 0, ap,      w0, w1, w2);
    grp(gbase + 1, ap + 16, w3, w4, w5);
    grp(gbase + 2, ap + 32, w6, w7, w8);
    grp(gbase + 3, ap + 48, w9, w10, w11);
  };

  for (int rep = 0; rep < REP; ++rep) {
    float4 xA0, xA1, xA2, xB0, xB1, xB2;
    if constexpr (STG) loadx(q0, xA0, xA1, xA2);

    for (int qq = 0; qq < NCH; qq += 2) {
      const int qa = (q0 + qq) & 7;
      const int qb = (q0 + qq + 1) & 7;

      if constexpr (STG) loadx(qb, xB0, xB1, xB2);
      __builtin_amdgcn_sched_barrier(0);
      if constexpr (STG) drain(xA0, xA1, xA2);
      bar();
      if constexpr (CMP) compute(qa);
      bar();

      if constexpr (STG) {
        if (qq + 2 < NCH) loadx((q0 + qq + 2) & 7, xA0, xA1, xA2);
      }
      __builtin_amdgcn_sched_barrier(0);
      if constexpr (STG) drain(xB0, xB1, xB2);
      bar();
      if constexpr (CMP) compute(qb);
      bar();
    }

    if constexpr (STG && !CMP) {   // keep drains alive (rule #17)
      unsigned short v = xl[(tid * 37 + rep * 101) % (BMF * XSTR)];
      asm volatile("" :: "v"((int)v));
    }
    if constexpr (EPI) {
      const int j  = lane & 3;
      const int ol = lane >> 2;
#pragma unroll 4
      for (int it = 0; it < 32; ++it) {
        int o = it * 128 + wave * 16 + ol;
        unsigned int v = *reinterpret_cast<const unsigned int*>(res + o * RSTRF + 2 * j);
        float b = bias[o];
        float lo = bf2f((unsigned short)(v & 0xffff)) + b;
        float hi = bf2f((unsigned short)(v >> 16)) + b;
        size_t base = (size_t)(b0 + 2 * j) * OUT_F + o;
        out[base]         = lo;
        out[base + OUT_F] = hi;
      }
    } else {                       // keep scatters alive (rule #17)
      unsigned short v = res[(tid * 53 + rep * 97) % (4096 * RSTRF)];
      asm volatile("" :: "v"((int)v));
    }
    bar();
  }
}

extern "C" void kernel_launch(void* const* d_in, const int* in_sizes, int n_in,
                              void* d_out, int out_size, void* d_ws, size_t ws_size,
                              hipStream_t stream) {
  const float* x    = (const float*)d_in[0];
  const float* w    = (const float*)d_in[1];
  const float* bias = (const float*)d_in[2];
  const float* mask = (const float*)d_in[3];
  float* out = (float*)d_out;

  unsigned short* wfrag = (unsigned short*)d_ws;   // 786432 B

  const int B = in_sizes[0] / IN_F;                // 16384
  dim3 grid(B / BMF);                              // 2048

  prep_wfrag<<<192, 256, 0, stream>>>(w, mask, wfrag);

  // Probes (write d_out with garbage; FULL overwrites everything after):
  sc_probe<13, 4><<<grid, 512, 0, stream>>>(x, bias, wfrag, out); // NOCOMPUTE: S+E+B
  sc_probe<14, 4><<<grid, 512, 0, stream>>>(x, bias, wfrag, out); // NOSTAGE:   C+E+B
  sc_probe<11, 4><<<grid, 512, 0, stream>>>(x, bias, wfrag, out); // NOEPI:     S+C+B
  sc_probe< 7, 4><<<grid, 512, 0, stream>>>(x, bias, wfrag, out); // NOBARRIER: S+C+E
  // The real kernel, last -> d_out final and correct:
  sc_probe<15, 1><<<grid, 512, 0, stream>>>(x, bias, wfrag, out); // FULL
}

// Round 14
// 266.749 us; speedup vs baseline: 23.4473x; 23.4473x over previous
//
#include <hip/hip_runtime.h>
#include <hip/hip_bf16.h>

#define IN_F 4096
#define OUT_F 4096
#define CPN 81
#define OINV 2225   // 81^{-1} mod 4096
#define OB16 2832   // 2225*16 mod 4096: o-step per group

#define BMF 8       // batch rows per block
#define NCH 16      // chunks
#define CHUNK 256   // cols per chunk
#define RSTRF 8     // res stride in shorts (16 B per o-row)

typedef __attribute__((ext_vector_type(4))) float f32x4;
typedef __attribute__((ext_vector_type(8))) short bf16x8;
typedef __attribute__((ext_vector_type(8))) unsigned short u16x8;

__device__ __forceinline__ unsigned short f2bf(float f) {
  __hip_bfloat16 h = __float2bfloat16(f);
  return *reinterpret_cast<unsigned short*>(&h);
}
__device__ __forceinline__ float bf2f(unsigned short u) {
  unsigned int v = ((unsigned int)u) << 16;
  return *reinterpret_cast<float*>(&v);
}

// ---- prep: pack weight*mask into MFMA B-fragment order ----
__global__ void prep_wfrag(const float* __restrict__ w,
                           const float* __restrict__ mask,
                           unsigned short* __restrict__ wfrag) {
  int idx = blockIdx.x * 256 + threadIdx.x;   // 49152 threads
  int lane = idx & 63;
  int t = (idx >> 6) % 3;
  int g = idx / 192;
  int n = lane & 15;
  int kg = lane >> 4;
  int s = g * 16 + n;
  int o = (OINV * s) & 4095;
  unsigned short v8[8];
#pragma unroll
  for (int i = 0; i < 8; ++i) {
    int c = 32 * t + 8 * kg + i;
    int j = c - n;
    float v = 0.f;
    if (j >= 0 && j < CPN) {
      int col = (16 * g + c) & 4095;
      v = w[(size_t)o * IN_F + col] * mask[(size_t)o * IN_F + col];
    }
    v8[i] = f2bf(v);
  }
  *reinterpret_cast<bf16x8*>(wfrag + (size_t)idx * 8) =
      *reinterpret_cast<const bf16x8*>(v8);
}

// ---- fused, wave-independent: NO block barriers in the chunk loop ----
// Each wave owns a private 8-row x 128-col slice (XOR-swizzled 16B granules)
// and 2 groups per chunk. One __syncthreads before the epilogue.
__global__ __launch_bounds__(512, 4) void sc_fused(
    const float* __restrict__ x, const float* __restrict__ bias,
    const unsigned short* __restrict__ wfrag, float* __restrict__ out) {
  __shared__ unsigned short res[4096 * RSTRF];   // 65536 B: [o][row] bf16
  __shared__ unsigned short xl[8 * 1024];        // 16384 B: [wave][row][16 gran]

  const int blk = blockIdx.x;        // 0..2047
  const int b0 = blk * BMF;
  const int tid = threadIdx.x;
  const int wave = tid >> 6;         // 0..7
  const int lane = tid & 63;
  const int ln = lane & 15;          // MFMA n index (s offset)
  const int lk = lane >> 4;          // k-group / D row quad
  const int r8 = lane & 7;           // staging row
  const int cq = lane >> 3;          // staging col-16 index (0..7)
  const int oln = (OINV * ln) & 4095;
  const int q0 = blk & 15;           // stagger chunk order across blocks

  const int wbase = wave << 10;      // wave * 1024 shorts (2 KB slice)
  const float* xrow = x + (size_t)(b0 + r8) * IN_F;

  auto loadx = [&](int q, float4& p0, float4& p1, float4& p2, float4& p3) {
    const int cb = q * CHUNK + 32 * wave + 16 * cq;
    p0 = *reinterpret_cast<const float4*>(xrow + ((cb     ) & 4095));
    p1 = *reinterpret_cast<const float4*>(xrow + ((cb +  4) & 4095));
    p2 = *reinterpret_cast<const float4*>(xrow + ((cb +  8) & 4095));
    p3 = *reinterpret_cast<const float4*>(xrow + ((cb + 12) & 4095));
  };
  auto drain = [&](const float4& p0, const float4& p1,
                   const float4& p2, const float4& p3) {
    u16x8 h;
    h[0]=f2bf(p0.x); h[1]=f2bf(p0.y); h[2]=f2bf(p0.z); h[3]=f2bf(p0.w);
    h[4]=f2bf(p1.x); h[5]=f2bf(p1.y); h[6]=f2bf(p1.z); h[7]=f2bf(p1.w);
    *reinterpret_cast<u16x8*>(
        &xl[wbase + (r8 << 7) + ((((2*cq  ) ^ r8) & 15) << 3)]) = h;
    h[0]=f2bf(p2.x); h[1]=f2bf(p2.y); h[2]=f2bf(p2.z); h[3]=f2bf(p2.w);
    h[4]=f2bf(p3.x); h[5]=f2bf(p3.y); h[6]=f2bf(p3.z); h[7]=f2bf(p3.w);
    *reinterpret_cast<u16x8*>(
        &xl[wbase + (r8 << 7) + ((((2*cq+1) ^ r8) & 15) << 3)]) = h;
  };
  auto frag = [&](int j, int t) -> bf16x8 {
    const int row = ln & 7;
    const int gr = 2*j + 4*t + lk;       // granule 0..13
    return *reinterpret_cast<const bf16x8*>(
        &xl[wbase + (row << 7) + (((gr ^ row) & 15) << 3)]);
  };
  auto scatter = [&](int g, f32x4 acc) {
    if (lk < 2) {                        // rows 0..7 (8..15 are dups)
      int o = (OB16 * g + oln) & 4095;
      ushort4 h;
      h.x = f2bf(acc[0]); h.y = f2bf(acc[1]);
      h.z = f2bf(acc[2]); h.w = f2bf(acc[3]);
      *reinterpret_cast<ushort4*>(&res[o * RSTRF + 4 * lk]) = h;
    }
  };
  auto compute = [&](int q) {
    const int g0 = q * 16 + 2 * wave;    // this wave's 2 groups
    const bf16x8* wf = reinterpret_cast<const bf16x8*>(wfrag)
                     + (size_t)g0 * 192 + lane;
    bf16x8 w0 = wf[0],   w1 = wf[64],  w2 = wf[128];
    bf16x8 w3 = wf[192], w4 = wf[256], w5 = wf[320];
    f32x4 acc = f32x4{0.f, 0.f, 0.f, 0.f};
    acc = __builtin_amdgcn_mfma_f32_16x16x32_bf16(frag(0,0), w0, acc, 0, 0, 0);
    acc = __builtin_amdgcn_mfma_f32_16x16x32_bf16(frag(0,1), w1, acc, 0, 0, 0);
    acc = __builtin_amdgcn_mfma_f32_16x16x32_bf16(frag(0,2), w2, acc, 0, 0, 0);
    scatter(g0, acc);
    acc = f32x4{0.f, 0.f, 0.f, 0.f};
    acc = __builtin_amdgcn_mfma_f32_16x16x32_bf16(frag(1,0), w3, acc, 0, 0, 0);
    acc = __builtin_amdgcn_mfma_f32_16x16x32_bf16(frag(1,1), w4, acc, 0, 0, 0);
    acc = __builtin_amdgcn_mfma_f32_16x16x32_bf16(frag(1,2), w5, acc, 0, 0, 0);
    scatter(g0 + 1, acc);
  };

  // ping-pong x register sets; loads pinned early by sched_barrier(0).
  float4 A0, A1, A2, A3, B0, B1, B2, B3;
  loadx(q0, A0, A1, A2, A3);

  for (int i = 0; i < NCH; i += 2) {
    const int qa = (q0 + i) & 15;
    const int qb = (q0 + i + 1) & 15;

    loadx(qb, B0, B1, B2, B3);             // next chunk's x in flight
    __builtin_amdgcn_sched_barrier(0);
    drain(A0, A1, A2, A3);                 // wave-private slice; no barrier
    compute(qa);

    if (i + 2 < NCH) loadx((q0 + i + 2) & 15, A0, A1, A2, A3);
    __builtin_amdgcn_sched_barrier(0);
    drain(B0, B1, B2, B3);
    compute(qb);
  }

  __syncthreads();   // res complete across all waves

  // ---- epilogue: out[b0+r][o] = res[o][r] + bias[o], full 64 B lines ----
  const int j  = lane & 3;          // row pair 2j, 2j+1
  const int ol = lane >> 2;         // 0..15 consecutive o
#pragma unroll 4
  for (int it = 0; it < 32; ++it) {
    int o = it * 128 + wave * 16 + ol;
    unsigned int v = *reinterpret_cast<const unsigned int*>(&res[o * RSTRF + 2 * j]);
    float b = bias[o];
    float lo = bf2f((unsigned short)(v & 0xffff)) + b;
    float hi = bf2f((unsigned short)(v >> 16)) + b;
    size_t base = (size_t)(b0 + 2 * j) * OUT_F + o;
    out[base]         = lo;
    out[base + OUT_F] = hi;
  }
}

extern "C" void kernel_launch(void* const* d_in, const int* in_sizes, int n_in,
                              void* d_out, int out_size, void* d_ws, size_t ws_size,
                              hipStream_t stream) {
  const float* x    = (const float*)d_in[0];
  const float* w    = (const float*)d_in[1];
  const float* bias = (const float*)d_in[2];
  const float* mask = (const float*)d_in[3];
  float* out = (float*)d_out;

  unsigned short* wfrag = (unsigned short*)d_ws;   // 786432 B

  const int B = in_sizes[0] / IN_F;                // 16384

  prep_wfrag<<<192, 256, 0, stream>>>(w, mask, wfrag);
  sc_fused<<<B / BMF, 512, 0, stream>>>(x, bias, wfrag, out);
}

// Round 15
// 189.370 us; speedup vs baseline: 33.0281x; 1.4086x over previous
//
#include <hip/hip_runtime.h>
#include <hip/hip_bf16.h>

#define IN_F 4096
#define OUT_F 4096
#define CPN 81
#define OINV 2225   // 81^{-1} mod 4096
#define OB16 2832   // 2225*16 mod 4096: o-step per group

#define BMF 8       // batch rows per block
#define NCH 8       // chunks per block
#define CHUNK 512   // band-starts (and x cols) per chunk
#define SC4 148     // float4 staged per row per chunk (592 cols)
#define NLD 1184    // BMF*SC4 loads per chunk
#define XSTR 616    // x LDS stride in shorts
#define RSTRF 8     // res stride in shorts (16 B per o-row)

typedef __attribute__((ext_vector_type(4))) float f32x4;
typedef __attribute__((ext_vector_type(8))) short bf16x8;

__device__ __forceinline__ unsigned short f2bf(float f) {
  __hip_bfloat16 h = __float2bfloat16(f);
  return *reinterpret_cast<unsigned short*>(&h);
}
__device__ __forceinline__ float bf2f(unsigned short u) {
  unsigned int v = ((unsigned int)u) << 16;
  return *reinterpret_cast<float*>(&v);
}

// ---- prep: pack weight*mask into MFMA B-fragment order ----
__global__ void prep_wfrag(const float* __restrict__ w,
                           const float* __restrict__ mask,
                           unsigned short* __restrict__ wfrag) {
  int idx = blockIdx.x * 256 + threadIdx.x;   // 49152 threads
  int lane = idx & 63;
  int t = (idx >> 6) % 3;
  int g = idx / 192;
  int n = lane & 15;
  int kg = lane >> 4;
  int s = g * 16 + n;
  int o = (OINV * s) & 4095;
  unsigned short v8[8];
#pragma unroll
  for (int i = 0; i < 8; ++i) {
    int c = 32 * t + 8 * kg + i;
    int j = c - n;
    float v = 0.f;
    if (j >= 0 && j < CPN) {
      int col = (16 * g + c) & 4095;
      v = w[(size_t)o * IN_F + col] * mask[(size_t)o * IN_F + col];
    }
    v8[i] = f2bf(v);
  }
  *reinterpret_cast<bf16x8*>(wfrag + (size_t)idx * 8) =
      *reinterpret_cast<const bf16x8*>(v8);
}

// ---- fused (R8 structure) + INTERLEAVED epilogue ----
// Out-line l (o in [16l,16l+16)) needs s in [1296l, 1296l+1296): complete
// after k chunks when a16 = (81l - 32*q0) mod 256 < 32k-80. Write newly
// completed lines right after each chunk's compute+sync.
__global__ __launch_bounds__(512, 4) void sc_fused(
    const float* __restrict__ x, const float* __restrict__ bias,
    const unsigned short* __restrict__ wfrag, float* __restrict__ out) {
  __shared__ unsigned short res[4096 * RSTRF];   // 65536 B: [o][row] bf16
  __shared__ unsigned short xl[BMF * XSTR];      //  9856 B

  const int blk = blockIdx.x;        // 0..2047
  const int b0 = blk * BMF;
  const int tid = threadIdx.x;
  const int wave = tid >> 6;         // 0..7
  const int lane = tid & 63;
  const int ln = lane & 15;          // MFMA n index (s offset)
  const int lk = lane >> 4;          // k-group / D row quad / epi row pair
  const int oln = (OINV * ln) & 4095;
  const int q0 = blk & 7;            // stagger chunk order across blocks

  // hoisted staging coordinates (3 load slots per thread)
  const int i1 = tid + 512, i2 = tid + 1024;
  const int row0 = tid / SC4, c40 = tid - row0 * SC4;
  const int row1 = i1 / SC4,  c41 = i1 - row1 * SC4;
  const int row2 = i2 / SC4,  c42 = i2 - row2 * SC4;
  const bool v2 = (i2 < NLD);
  const float* xp0 = x + (size_t)(b0 + row0) * IN_F;
  const float* xp1 = x + (size_t)(b0 + row1) * IN_F;
  const float* xp2 = x + (size_t)(b0 + row2) * IN_F;
  unsigned short* xw0 = xl + row0 * XSTR + 4 * c40;
  unsigned short* xw1 = xl + row1 * XSTR + 4 * c41;
  unsigned short* xw2 = xl + row2 * XSTR + 4 * c42;

  auto loadx = [&](int q, float4& r0, float4& r1, float4& r2) {
    const int c0 = q * CHUNK;
    r0 = *reinterpret_cast<const float4*>(xp0 + ((c0 + 4 * c40) & 4095));
    r1 = *reinterpret_cast<const float4*>(xp1 + ((c0 + 4 * c41) & 4095));
    if (v2) r2 = *reinterpret_cast<const float4*>(xp2 + ((c0 + 4 * c42) & 4095));
  };
  auto drain = [&](const float4& r0, const float4& r1, const float4& r2) {
    ushort4 h;
    h.x = f2bf(r0.x); h.y = f2bf(r0.y); h.z = f2bf(r0.z); h.w = f2bf(r0.w);
    *reinterpret_cast<ushort4*>(xw0) = h;
    h.x = f2bf(r1.x); h.y = f2bf(r1.y); h.z = f2bf(r1.z); h.w = f2bf(r1.w);
    *reinterpret_cast<ushort4*>(xw1) = h;
    if (v2) {
      h.x = f2bf(r2.x); h.y = f2bf(r2.y); h.z = f2bf(r2.z); h.w = f2bf(r2.w);
      *reinterpret_cast<ushort4*>(xw2) = h;
    }
  };
  auto grp = [&](int g, const unsigned short* ap,
                 bf16x8 b0f, bf16x8 b1f, bf16x8 b2f) {
    bf16x8 a0 = *reinterpret_cast<const bf16x8*>(ap);
    bf16x8 a1 = *reinterpret_cast<const bf16x8*>(ap + 32);
    bf16x8 a2 = *reinterpret_cast<const bf16x8*>(ap + 64);
    f32x4 acc = f32x4{0.f, 0.f, 0.f, 0.f};
    acc = __builtin_amdgcn_mfma_f32_16x16x32_bf16(a0, b0f, acc, 0, 0, 0);
    acc = __builtin_amdgcn_mfma_f32_16x16x32_bf16(a1, b1f, acc, 0, 0, 0);
    acc = __builtin_amdgcn_mfma_f32_16x16x32_bf16(a2, b2f, acc, 0, 0, 0);
    if (lk < 2) {                    // rows 0..7 (8..15 are dups)
      int o = (OB16 * g + oln) & 4095;
      ushort4 h;
      h.x = f2bf(acc[0]); h.y = f2bf(acc[1]);
      h.z = f2bf(acc[2]); h.w = f2bf(acc[3]);
      *reinterpret_cast<ushort4*>(res + o * RSTRF + 4 * lk) = h;
    }
  };
  auto compute = [&](int q) {
    const int gbase = q * 32 + wave * 4;
    const bf16x8* wf = reinterpret_cast<const bf16x8*>(wfrag)
                     + (size_t)gbase * 192 + lane;
    bf16x8 w0 = wf[0],   w1 = wf[64],  w2  = wf[128];
    bf16x8 w3 = wf[192], w4 = wf[256], w5  = wf[320];
    bf16x8 w6 = wf[384], w7 = wf[448], w8  = wf[512];
    bf16x8 w9 = wf[576], w10 = wf[640], w11 = wf[704];
    const unsigned short* ap = xl + (ln & 7) * XSTR + 8 * lk + 16 * (wave * 4);
    grp(gbase + 0, ap,      w0, w1, w2);
    grp(gbase + 1, ap + 16, w3, w4, w5);
    grp(gbase + 2, ap + 32, w6, w7, w8);
    grp(gbase + 3, ap + 48, w9, w10, w11);
  };
  // interleaved epilogue: lines with a16 in [lo,hi); 1 line per wave-step
  auto epi = [&](int lo, int hi) {
    for (int li = lo + wave; li < hi; li += 8) {
      int l = (177 * (li + 32 * q0)) & 255;   // 177 = 81^{-1} mod 256
      int o = 16 * l + ln;
      unsigned int v = *reinterpret_cast<const unsigned int*>(
          &res[o * RSTRF + 2 * lk]);
      float b = bias[o];
      size_t base = (size_t)(b0 + 2 * lk) * OUT_F + o;
      out[base]         = bf2f((unsigned short)(v & 0xffff)) + b;
      out[base + OUT_F] = bf2f((unsigned short)(v >> 16)) + b;
    }
  };
  // completed-line bound after k chunks
  auto ebound = [](int k) -> int {
    return k < 3 ? 0 : (k >= NCH ? 256 : 32 * k - 80);
  };

  // ping-pong x register sets A/B; loads pinned early by sched_barrier(0)
  float4 xA0, xA1, xA2, xB0, xB1, xB2;
  loadx(q0, xA0, xA1, xA2);

  for (int qq = 0; qq < NCH; qq += 2) {
    const int qa = (q0 + qq) & 7;
    const int qb = (q0 + qq + 1) & 7;

    loadx(qb, xB0, xB1, xB2);              // issue early...
    __builtin_amdgcn_sched_barrier(0);     // ...and pin: cannot sink below
    drain(xA0, xA1, xA2);
    __syncthreads();
    compute(qa);
    __syncthreads();
    epi(ebound(qq), ebound(qq + 1));       // k = qq+1 chunks done

    if (qq + 2 < NCH) {
      loadx((q0 + qq + 2) & 7, xA0, xA1, xA2);
      __builtin_amdgcn_sched_barrier(0);
    }
    drain(xB0, xB1, xB2);
    __syncthreads();
    compute(qb);
    __syncthreads();
    epi(ebound(qq + 1), ebound(qq + 2));   // k = qq+2 chunks done
  }
}

extern "C" void kernel_launch(void* const* d_in, const int* in_sizes, int n_in,
                              void* d_out, int out_size, void* d_ws, size_t ws_size,
                              hipStream_t stream) {
  const float* x    = (const float*)d_in[0];
  const float* w    = (const float*)d_in[1];
  const float* bias = (const float*)d_in[2];
  const float* mask = (const float*)d_in[3];
  float* out = (float*)d_out;

  unsigned short* wfrag = (unsigned short*)d_ws;   // 786432 B

  const int B = in_sizes[0] / IN_F;                // 16384

  prep_wfrag<<<192, 256, 0, stream>>>(w, mask, wfrag);
  sc_fused<<<B / BMF, 512, 0, stream>>>(x, bias, wfrag, out);
}

// Round 16
// 161.490 us; speedup vs baseline: 38.7304x; 1.1726x over previous
//
#include <hip/hip_runtime.h>
#include <hip/hip_bf16.h>

#define IN_F 4096
#define OUT_F 4096
#define CPN 81
#define OINV 2225   // 81^{-1} mod 4096
#define OB16 2832   // 2225*16 mod 4096: o-step per group

#define BMF 8       // batch rows per block
#define NCH 8       // chunks per block
#define CHUNK 512   // band-starts (and x cols) per chunk
#define SC4 148     // float4 staged per row per chunk (592 cols)
#define NLD 1184    // BMF*SC4 loads per chunk
#define XSTR 616    // x LDS stride in shorts
#define RSTRF 8     // res stride in shorts (16 B per o-row)

typedef __attribute__((ext_vector_type(4))) float f32x4;
typedef __attribute__((ext_vector_type(8))) short bf16x8;

__device__ __forceinline__ unsigned short f2bf(float f) {
  __hip_bfloat16 h = __float2bfloat16(f);
  return *reinterpret_cast<unsigned short*>(&h);
}
__device__ __forceinline__ float bf2f(unsigned short u) {
  unsigned int v = ((unsigned int)u) << 16;
  return *reinterpret_cast<float*>(&v);
}

// ---- prep: pack weight*mask into MFMA B-fragment order ----
// Band condition 0 <= c-n < 81 IS the mask (mask[o][col]=1 iff col=s+j,
// j in [0,81), s = 81*o mod 4096 = our s): mask load dropped as redundant.
__global__ void prep_wfrag(const float* __restrict__ w,
                           unsigned short* __restrict__ wfrag) {
  int idx = blockIdx.x * 256 + threadIdx.x;   // 49152 threads
  int lane = idx & 63;
  int t = (idx >> 6) % 3;
  int g = idx / 192;
  int n = lane & 15;
  int kg = lane >> 4;
  int s = g * 16 + n;
  int o = (OINV * s) & 4095;
  unsigned short v8[8];
#pragma unroll
  for (int i = 0; i < 8; ++i) {
    int c = 32 * t + 8 * kg + i;
    int j = c - n;
    float v = 0.f;
    if (j >= 0 && j < CPN) {
      int col = (16 * g + c) & 4095;
      v = w[(size_t)o * IN_F + col];
    }
    v8[i] = f2bf(v);
  }
  *reinterpret_cast<bf16x8*>(wfrag + (size_t)idx * 8) =
      *reinterpret_cast<const bf16x8*>(v8);
}

// ---- fused: x ping-pong + STREAMING wf prefetch (refill-after-consume) ----
__global__ __launch_bounds__(512, 4) void sc_fused(
    const float* __restrict__ x, const float* __restrict__ bias,
    const unsigned short* __restrict__ wfrag, float* __restrict__ out) {
  __shared__ unsigned short res[4096 * RSTRF];   // 65536 B: [o][row] bf16
  __shared__ unsigned short xl[BMF * XSTR];      //  9856 B

  const int blk = blockIdx.x;        // 0..2047
  const int b0 = blk * BMF;
  const int tid = threadIdx.x;
  const int wave = tid >> 6;         // 0..7
  const int lane = tid & 63;
  const int ln = lane & 15;          // MFMA n index (s offset)
  const int lk = lane >> 4;          // k-group / D row quad
  const int oln = (OINV * ln) & 4095;
  const int q0 = blk & 7;            // stagger chunk order across blocks

  // hoisted staging coordinates (3 load slots per thread)
  const int i1 = tid + 512, i2 = tid + 1024;
  const int row0 = tid / SC4, c40 = tid - row0 * SC4;
  const int row1 = i1 / SC4,  c41 = i1 - row1 * SC4;
  const int row2 = i2 / SC4,  c42 = i2 - row2 * SC4;
  const bool v2 = (i2 < NLD);
  const float* xp0 = x + (size_t)(b0 + row0) * IN_F;
  const float* xp1 = x + (size_t)(b0 + row1) * IN_F;
  const float* xp2 = x + (size_t)(b0 + row2) * IN_F;
  unsigned short* xw0 = xl + row0 * XSTR + 4 * c40;
  unsigned short* xw1 = xl + row1 * XSTR + 4 * c41;
  unsigned short* xw2 = xl + row2 * XSTR + 4 * c42;

  auto loadx = [&](int q, float4& r0, float4& r1, float4& r2) {
    const int c0 = q * CHUNK;
    r0 = *reinterpret_cast<const float4*>(xp0 + ((c0 + 4 * c40) & 4095));
    r1 = *reinterpret_cast<const float4*>(xp1 + ((c0 + 4 * c41) & 4095));
    if (v2) r2 = *reinterpret_cast<const float4*>(xp2 + ((c0 + 4 * c42) & 4095));
  };
  auto drain = [&](const float4& r0, const float4& r1, const float4& r2) {
    ushort4 h;
    h.x = f2bf(r0.x); h.y = f2bf(r0.y); h.z = f2bf(r0.z); h.w = f2bf(r0.w);
    *reinterpret_cast<ushort4*>(xw0) = h;
    h.x = f2bf(r1.x); h.y = f2bf(r1.y); h.z = f2bf(r1.z); h.w = f2bf(r1.w);
    *reinterpret_cast<ushort4*>(xw1) = h;
    if (v2) {
      h.x = f2bf(r2.x); h.y = f2bf(r2.y); h.z = f2bf(r2.z); h.w = f2bf(r2.w);
      *reinterpret_cast<ushort4*>(xw2) = h;
    }
  };
  auto grp = [&](int g, const unsigned short* ap,
                 bf16x8 b0f, bf16x8 b1f, bf16x8 b2f) {
    bf16x8 a0 = *reinterpret_cast<const bf16x8*>(ap);
    bf16x8 a1 = *reinterpret_cast<const bf16x8*>(ap + 32);
    bf16x8 a2 = *reinterpret_cast<const bf16x8*>(ap + 64);
    f32x4 acc = f32x4{0.f, 0.f, 0.f, 0.f};
    acc = __builtin_amdgcn_mfma_f32_16x16x32_bf16(a0, b0f, acc, 0, 0, 0);
    acc = __builtin_amdgcn_mfma_f32_16x16x32_bf16(a1, b1f, acc, 0, 0, 0);
    acc = __builtin_amdgcn_mfma_f32_16x16x32_bf16(a2, b2f, acc, 0, 0, 0);
    if (lk < 2) {                    // rows 0..7 (8..15 are dups)
      int o = (OB16 * g + oln) & 4095;
      ushort4 h;
      h.x = f2bf(acc[0]); h.y = f2bf(acc[1]);
      h.z = f2bf(acc[2]); h.w = f2bf(acc[3]);
      *reinterpret_cast<ushort4*>(res + o * RSTRF + 4 * lk) = h;
    }
  };

  // loop-carried wf register set: chunk q's 12 B-fragments.
  bf16x8 w0, w1, w2, w3, w4, w5, w6, w7, w8, w9, w10, w11;
  const bf16x8* wfb = reinterpret_cast<const bf16x8*>(wfrag)
                    + (size_t)(wave * 4) * 192 + lane;
  {
    const bf16x8* wf = wfb + (size_t)(q0 * 32) * 192;
    w0 = wf[0];   w1 = wf[64];  w2  = wf[128];
    w3 = wf[192]; w4 = wf[256]; w5  = wf[320];
    w6 = wf[384]; w7 = wf[448]; w8  = wf[512];
    w9 = wf[576]; w10 = wf[640]; w11 = wf[704];
  }
  // compute chunk q from resident w0..w11, refilling each trio for chunk qn
  // immediately after its group's MFMAs consume it (prefetch distance ~1 phase)
  auto compute = [&](int q, int qn) {
    const int gbase = q * 32 + wave * 4;
    const bf16x8* wfn = wfb + (size_t)(qn * 32) * 192;
    const unsigned short* ap = xl + (ln & 7) * XSTR + 8 * lk + 16 * (wave * 4);
    grp(gbase + 0, ap,      w0, w1, w2);
    w0 = wfn[0];   w1 = wfn[64];  w2  = wfn[128];
    grp(gbase + 1, ap + 16, w3, w4, w5);
    w3 = wfn[192]; w4 = wfn[256]; w5  = wfn[320];
    grp(gbase + 2, ap + 32, w6, w7, w8);
    w6 = wfn[384]; w7 = wfn[448]; w8  = wfn[512];
    grp(gbase + 3, ap + 48, w9, w10, w11);
    w9 = wfn[576]; w10 = wfn[640]; w11 = wfn[704];
  };

  // ping-pong x register sets A/B; loads pinned early by sched_barrier(0)
  float4 xA0, xA1, xA2, xB0, xB1, xB2;
  loadx(q0, xA0, xA1, xA2);

  for (int qq = 0; qq < NCH; qq += 2) {
    const int qa = (q0 + qq) & 7;
    const int qb = (q0 + qq + 1) & 7;

    loadx(qb, xB0, xB1, xB2);              // issue early...
    __builtin_amdgcn_sched_barrier(0);     // ...and pin: cannot sink below
    drain(xA0, xA1, xA2);
    __syncthreads();
    compute(qa, qb);                       // stream-prefetch qb's wf
    __syncthreads();

    if (qq + 2 < NCH) {
      loadx((q0 + qq + 2) & 7, xA0, xA1, xA2);
      __builtin_amdgcn_sched_barrier(0);
    }
    drain(xB0, xB1, xB2);
    __syncthreads();
    compute(qb, (q0 + qq + 2) & 7);        // last iter: harmless wrap reload
    __syncthreads();
  }

  // ---- epilogue: out[b0+r][o] = res[o][r] + bias[o] ----
  // lane = (ol, j): b32 read at byte 16o+4j -> bank 4(o&7)+j: 2-way max.
  const int j  = lane & 3;          // row pair 2j, 2j+1
  const int ol = lane >> 2;         // 0..15 consecutive o
#pragma unroll 4
  for (int it = 0; it < 32; ++it) {
    int o = it * 128 + wave * 16 + ol;
    unsigned int v = *reinterpret_cast<const unsigned int*>(res + o * RSTRF + 2 * j);
    float b = bias[o];
    float lo = bf2f((unsigned short)(v & 0xffff)) + b;
    float hi = bf2f((unsigned short)(v >> 16)) + b;
    size_t base = (size_t)(b0 + 2 * j) * OUT_F + o;
    out[base]         = lo;
    out[base + OUT_F] = hi;
  }
}

extern "C" void kernel_launch(void* const* d_in, const int* in_sizes, int n_in,
                              void* d_out, int out_size, void* d_ws, size_t ws_size,
                              hipStream_t stream) {
  const float* x    = (const float*)d_in[0];
  const float* w    = (const float*)d_in[1];
  const float* bias = (const float*)d_in[2];
  float* out = (float*)d_out;

  unsigned short* wfrag = (unsigned short*)d_ws;   // 786432 B

  const int B = in_sizes[0] / IN_F;                // 16384

  prep_wfrag<<<192, 256, 0, stream>>>(w, wfrag);
  sc_fused<<<B / BMF, 512, 0, stream>>>(x, bias, wfrag, out);
}